// Round 16
// baseline (371.380 us; speedup 1.0000x reference)
//
#include <hip/hip_runtime.h>
#include <math.h>

#define N_NODES 50000
#define N_EDGES 1000000
#define HID 64
#define SCAN_NB ((N_NODES + 1 + 255) / 256)
#define N_TILES (N_NODES / 16)          // 3125
#define NB_F ((N_TILES + 3) / 4)        // 782 mlp blocks (4 waves each)
#define NB2 64                          // stage-2 reduction blocks
static_assert(N_NODES % 16 == 0, "tile math");
static_assert(N_NODES <= 65536, "src must fit in 16 bits");

typedef __attribute__((ext_vector_type(8))) short short8;   // 8 bf16 = 4 VGPRs
typedef __attribute__((ext_vector_type(4))) float f32x4;

__device__ __forceinline__ unsigned short f2bf(float x) {   // RNE float->bf16
    unsigned u = __float_as_uint(x);
    u += 0x7FFFu + ((u >> 16) & 1u);
    return (unsigned short)(u >> 16);
}
__device__ __forceinline__ float bfbits_hi(unsigned pk) {   // high-16 bf16 -> f32
    return __uint_as_float(pk & 0xFFFF0000u);
}
__device__ __forceinline__ float bf2f(unsigned short v) {
    return __uint_as_float(((unsigned)v) << 16);
}
// packed bf16 pair add with RNE re-round
__device__ __forceinline__ unsigned addpk(unsigned a, unsigned b) {
    float lo = __uint_as_float(a << 16) + __uint_as_float(b << 16);
    float hi = __uint_as_float(a & 0xFFFF0000u) + __uint_as_float(b & 0xFFFF0000u);
    return (unsigned)f2bf(lo) | ((unsigned)f2bf(hi) << 16);
}

// ---------------- node encoder: zb = bf16(x @ W_node + b_node) ----------------
__global__ __launch_bounds__(256) void k_node_encode(
    const float* __restrict__ x, const float* __restrict__ Wn,
    const float* __restrict__ bn, unsigned short* __restrict__ zb) {
    int n = blockIdx.x * 4 + (threadIdx.x >> 6);
    int c = threadIdx.x & 63;
    if (n >= N_NODES) return;
    float acc = bn[c];
    const float* xr = x + n * 16;
    #pragma unroll
    for (int k = 0; k < 16; ++k) acc = fmaf(xr[k], Wn[k * 64 + c], acc);
    zb[n * 64 + c] = f2bf(acc);
}

// ---------------- weight prep: pack W1/W2 (3 layers) into bf16 fragment order ----------------
// w1p[L*8192 + ((s*8+t)*64 + lane)*8 + j] = bf16(W1[L][s*32+quad*8+j][t*16+col])
// w2p[L*8192 + ((s*4+t)*64 + lane)*8 + j] = bf16(W2[L][s*32+quad*8+j][t*16+col])
__global__ __launch_bounds__(256) void k_wprep(
    const float* __restrict__ W1, const float* __restrict__ W2,
    unsigned short* __restrict__ w1p, unsigned short* __restrict__ w2p) {
    int i = blockIdx.x * 256 + threadIdx.x;
    if (i >= 3 * 8192) return;
    int L = i >> 13, r = i & 8191;
    int j = r & 7, lane = (r >> 3) & 63;
    int quad = lane >> 4, col = lane & 15;
    {
        int st = r >> 9;                 // 0..15: s=st>>3 (2), t=st&7 (8)
        int s = st >> 3, t = st & 7;
        w1p[i] = f2bf(W1[L * 8192 + (s * 32 + quad * 8 + j) * 128 + t * 16 + col]);
    }
    {
        int ft = r >> 9;                 // 0..15: s=ft>>2 (4), t=ft&3 (4)
        int s = ft >> 2, t = ft & 3;
        w2p[i] = f2bf(W2[L * 8192 + (s * 32 + quad * 8 + j) * 64 + t * 16 + col]);
    }
}

// ---------------- edge CSR build ----------------
__global__ __launch_bounds__(256) void k_hist_rank(const int* __restrict__ ei,
                                                   int* __restrict__ cnt, int* __restrict__ rank) {
    int i = blockIdx.x * blockDim.x + threadIdx.x;
    if (i >= N_EDGES) return;
    rank[i] = atomicAdd(&cnt[ei[N_EDGES + i]], 1);
}

__global__ __launch_bounds__(256) void k_scan1(const int* __restrict__ cnt,
                                               int* __restrict__ inc, int* __restrict__ bsum) {
    __shared__ int sh[256];
    int gi = blockIdx.x * 256 + threadIdx.x;
    int v = (gi < N_NODES + 1) ? cnt[gi] : 0;
    sh[threadIdx.x] = v;
    __syncthreads();
    #pragma unroll
    for (int d = 1; d < 256; d <<= 1) {
        int t = (threadIdx.x >= d) ? sh[threadIdx.x - d] : 0;
        __syncthreads();
        sh[threadIdx.x] += t;
        __syncthreads();
    }
    if (gi < N_NODES + 1) inc[gi] = sh[threadIdx.x];
    if (threadIdx.x == 255) bsum[blockIdx.x] = sh[255];
}

__global__ __launch_bounds__(256) void k_scan2(int* __restrict__ bsum) {
    __shared__ int sh[256];
    int t = threadIdx.x;
    sh[t] = (t < SCAN_NB) ? bsum[t] : 0;
    __syncthreads();
    #pragma unroll
    for (int d = 1; d < 256; d <<= 1) {
        int v = (t >= d) ? sh[t - d] : 0;
        __syncthreads();
        sh[t] += v;
        __syncthreads();
    }
    if (t < SCAN_NB) bsum[t] = (t == 0) ? 0 : sh[t - 1];
}

__global__ __launch_bounds__(256) void k_scan3(const int* __restrict__ inc,
                                               const int* __restrict__ cnt,
                                               const int* __restrict__ bsum,
                                               int* __restrict__ offs) {
    int gi = blockIdx.x * 256 + threadIdx.x;
    if (gi < N_NODES + 1) offs[gi] = bsum[blockIdx.x] + inc[gi] - cnt[gi];
}

__global__ __launch_bounds__(256) void k_scatter(
    const int* __restrict__ ei, const float* __restrict__ eattr,
    const int* __restrict__ offs, const int* __restrict__ rank,
    unsigned int* __restrict__ s_pack) {
    int i = blockIdx.x * blockDim.x + threadIdx.x;
    if (i >= N_EDGES) return;
    int d = ei[N_EDGES + i];
    int p = offs[d] + rank[i];
    unsigned pk = ((unsigned)f2bf(eattr[i]) << 16) | (unsigned)(ei[i] & 0xFFFF);
    s_pack[p] = pk;
}

// ---------------- softmax aggregation (shift-free), one wave/node, 8-edge ILP ----------------
__global__ __launch_bounds__(256) void k_agg(
    const unsigned short* __restrict__ zb, const int* __restrict__ offs,
    const unsigned int* __restrict__ s_pack,
    const float* __restrict__ We, const float* __restrict__ be,
    const float* __restrict__ t, int layer, unsigned short* __restrict__ aggb) {
    int wid = (blockIdx.x * blockDim.x + threadIdx.x) >> 6;
    int lane = threadIdx.x & 63;
    if (wid >= N_NODES) return;
    int beg = offs[wid], end = offs[wid + 1];
    float we = We[lane], bev = be[lane];
    float tl = t[layer];
    float s = 0.f, num = 0.f;
    int i = beg;
    for (; i + 7 < end; i += 8) {
        unsigned pk[8];
        #pragma unroll
        for (int j = 0; j < 8; ++j) pk[j] = s_pack[i + j];
        float zv[8];
        #pragma unroll
        for (int j = 0; j < 8; ++j) zv[j] = bf2f(zb[(pk[j] & 0xFFFFu) * 64 + lane]);
        float acc_s = 0.f, acc_n = 0.f;
        #pragma unroll
        for (int j = 0; j < 8; ++j) {
            float msg = fmaxf(zv[j] + fmaf(bfbits_hi(pk[j]), we, bev), 0.f) + 1e-7f;
            float p = __expf(msg * tl);
            acc_s += p;
            acc_n = fmaf(p, msg, acc_n);
        }
        s += acc_s;
        num += acc_n;
    }
    for (; i < end; ++i) {
        unsigned pk = s_pack[i];
        float zz = bf2f(zb[(pk & 0xFFFFu) * 64 + lane]);
        float msg = fmaxf(zz + fmaf(bfbits_hi(pk), we, bev), 0.f) + 1e-7f;
        float p = __expf(msg * tl);
        s += p;
        num = fmaf(p, msg, num);
    }
    aggb[wid * 64 + lane] = f2bf(num / (s + 1e-16f));
}

// ---------------- MFMA MLP + fused epilogue (weights from packed bf16 fragments) ----------------
// mode 0: layer0 — no residual, write hb, zb <- relu(LN(h, ng, nb)) in place
// mode 1: layer1 — residual,    write hb, zb <- relu(LN(h, ng, nb)) in place
// mode 2: layer2 — residual, no hb write, pool partials with ng/nb
__global__ __launch_bounds__(256) void k_mlp(
    const unsigned short* __restrict__ aggb, unsigned short* __restrict__ zb,
    unsigned short* __restrict__ hb,
    const unsigned short* __restrict__ w1p, const unsigned short* __restrict__ w2p,
    const float* __restrict__ b1,
    const float* __restrict__ g1, const float* __restrict__ be1,
    const float* __restrict__ b2,
    const float* __restrict__ ng, const float* __restrict__ nb, int mode,
    float* __restrict__ pb_sum, float* __restrict__ pb_max) {
    __shared__ unsigned short vbuf[4][16 * 64];
    __shared__ unsigned short ubuf[4][16 * 128];
    __shared__ float lssum[4][4][16], lsmax[4][4][16];
    int lane = threadIdx.x & 63;
    int wave = threadIdx.x >> 6;
    int col = lane & 15, quad = lane >> 4;
    unsigned short* vb = vbuf[wave];
    unsigned short* ub = ubuf[wave];

    // weight fragments: coalesced dwordx4 loads from packed, L2-hot buffers
    short8 w1f[2][8];
    #pragma unroll
    for (int s = 0; s < 2; ++s)
        #pragma unroll
        for (int t = 0; t < 8; ++t)
            w1f[s][t] = *(const short8*)&w1p[(((s * 8 + t) * 64) + lane) * 8];
    short8 w2f[4][4];
    #pragma unroll
    for (int s = 0; s < 4; ++s)
        #pragma unroll
        for (int t = 0; t < 4; ++t)
            w2f[s][t] = *(const short8*)&w2p[(((s * 4 + t) * 64) + lane) * 8];

    float b1f[8], g1f[8], e1f[8];
    #pragma unroll
    for (int t = 0; t < 8; ++t) {
        int ch = t * 16 + col;
        b1f[t] = b1[ch]; g1f[t] = g1[ch]; e1f[t] = be1[ch];
    }
    float b2f_[4], ngf[4], nbf[4];
    #pragma unroll
    for (int t = 0; t < 4; ++t) {
        b2f_[t] = b2[t * 16 + col];
        ngf[t] = ng[t * 16 + col];
        nbf[t] = nb[t * 16 + col];
    }

    float psum[4] = {0.f, 0.f, 0.f, 0.f};
    float pmax[4] = {0.f, 0.f, 0.f, 0.f};
    int nd = lane >> 2;
    int cg = (lane & 3) * 16;
    int tile = blockIdx.x * 4 + wave;

    if (tile < N_TILES) {
        int n0 = tile * 16;
        const uint4* ap = (const uint4*)(aggb + (size_t)(n0 + nd) * 64 + cg);
        const uint4* zp = (const uint4*)(zb + (size_t)(n0 + nd) * 64 + cg);
        uint4 a0 = ap[0], a1 = ap[1], z0 = zp[0], z1 = zp[1];
        uint4 r0, r1;
        r0.x = addpk(a0.x, z0.x); r0.y = addpk(a0.y, z0.y);
        r0.z = addpk(a0.z, z0.z); r0.w = addpk(a0.w, z0.w);
        r1.x = addpk(a1.x, z1.x); r1.y = addpk(a1.y, z1.y);
        r1.z = addpk(a1.z, z1.z); r1.w = addpk(a1.w, z1.w);
        uint4* vdst = (uint4*)&vb[nd * 64 + cg];
        vdst[0] = r0;
        vdst[1] = r1;

        // GEMM1
        short8 af0 = *(const short8*)&vb[col * 64 + quad * 8];
        short8 af1 = *(const short8*)&vb[col * 64 + 32 + quad * 8];
        f32x4 au[8];
        #pragma unroll
        for (int t = 0; t < 8; ++t) {
            f32x4 c = {0.f, 0.f, 0.f, 0.f};
            c = __builtin_amdgcn_mfma_f32_16x16x32_bf16(af0, w1f[0][t], c, 0, 0, 0);
            c = __builtin_amdgcn_mfma_f32_16x16x32_bf16(af1, w1f[1][t], c, 0, 0, 0);
            au[t] = c;
        }
        // LN(128)+relu -> ub
        #pragma unroll
        for (int r = 0; r < 4; ++r) {
            float sx = 0.f, sq = 0.f;
            #pragma unroll
            for (int t = 0; t < 8; ++t) {
                float v = au[t][r] + b1f[t];
                sx += v; sq += v * v;
            }
            #pragma unroll
            for (int mask = 1; mask < 16; mask <<= 1) {
                sx += __shfl_xor(sx, mask, 64);
                sq += __shfl_xor(sq, mask, 64);
            }
            float mu = sx * (1.f / 128.f);
            float var = sq * (1.f / 128.f) - mu * mu;
            float rs = rsqrtf(var + 1e-5f);
            int row = quad * 4 + r;
            #pragma unroll
            for (int t = 0; t < 8; ++t) {
                float v = au[t][r] + b1f[t];
                float y = fmaxf(fmaf((v - mu) * rs, g1f[t], e1f[t]), 0.f);
                ub[row * 128 + t * 16 + col] = f2bf(y);
            }
        }
        // GEMM2
        f32x4 oc[4];
        #pragma unroll
        for (int t = 0; t < 4; ++t) oc[t] = (f32x4){0.f, 0.f, 0.f, 0.f};
        #pragma unroll
        for (int s = 0; s < 4; ++s) {
            short8 a = *(const short8*)&ub[col * 128 + s * 32 + quad * 8];
            #pragma unroll
            for (int t = 0; t < 4; ++t)
                oc[t] = __builtin_amdgcn_mfma_f32_16x16x32_bf16(a, w2f[s][t], oc[t], 0, 0, 0);
        }
        // epilogue
        #pragma unroll
        for (int r = 0; r < 4; ++r) {
            int n = n0 + quad * 4 + r;
            float val[4];
            #pragma unroll
            for (int t = 0; t < 4; ++t) {
                val[t] = oc[t][r] + b2f_[t];
                if (mode >= 1) val[t] += bf2f(hb[(size_t)n * 64 + t * 16 + col]);
            }
            if (mode <= 1) {
                #pragma unroll
                for (int t = 0; t < 4; ++t) hb[(size_t)n * 64 + t * 16 + col] = f2bf(val[t]);
            }
            float sx = 0.f, sq = 0.f;
            #pragma unroll
            for (int t = 0; t < 4; ++t) { sx += val[t]; sq += val[t] * val[t]; }
            #pragma unroll
            for (int mask = 1; mask < 16; mask <<= 1) {
                sx += __shfl_xor(sx, mask, 64);
                sq += __shfl_xor(sq, mask, 64);
            }
            float mu = sx * (1.f / 64.f);
            float var = sq * (1.f / 64.f) - mu * mu;
            float rs = rsqrtf(var + 1e-5f);
            #pragma unroll
            for (int t = 0; t < 4; ++t) {
                float y = fmaxf(fmaf((val[t] - mu) * rs, ngf[t], nbf[t]), 0.f);
                if (mode <= 1) {
                    zb[(size_t)n * 64 + t * 16 + col] = f2bf(y);
                } else {
                    psum[t] += y;
                    pmax[t] = fmaxf(pmax[t], y);
                }
            }
        }
    }
    if (mode == 2) {
        #pragma unroll
        for (int t = 0; t < 4; ++t) {
            psum[t] += __shfl_xor(psum[t], 16, 64);
            psum[t] += __shfl_xor(psum[t], 32, 64);
            pmax[t] = fmaxf(pmax[t], __shfl_xor(pmax[t], 16, 64));
            pmax[t] = fmaxf(pmax[t], __shfl_xor(pmax[t], 32, 64));
        }
        if (quad == 0) {
            #pragma unroll
            for (int t = 0; t < 4; ++t) {
                lssum[wave][t][col] = psum[t];
                lsmax[wave][t][col] = pmax[t];
            }
        }
        __syncthreads();
        if (wave == 0) {
            int t = lane >> 4, c = lane & 15;
            float s = lssum[0][t][c] + lssum[1][t][c] + lssum[2][t][c] + lssum[3][t][c];
            float mx = fmaxf(fmaxf(lsmax[0][t][c], lsmax[1][t][c]),
                             fmaxf(lsmax[2][t][c], lsmax[3][t][c]));
            pb_sum[blockIdx.x * 64 + lane] = s;
            pb_max[blockIdx.x * 64 + lane] = mx;
        }
    }
}

// ---------------- stage-2 reduce: 782 partial rows -> 64 rows ----------------
__global__ __launch_bounds__(256) void k_red(
    const float* __restrict__ pb_sum, const float* __restrict__ pb_max,
    float* __restrict__ p2_sum, float* __restrict__ p2_max) {
    __shared__ float sa4[4][64], sm4[4][64];
    int t = threadIdx.x;
    int ch = t & 63, part = t >> 6;
    float s = 0.f, mx = 0.f;
    for (int b = blockIdx.x + NB2 * part; b < NB_F; b += NB2 * 4) {
        s += pb_sum[b * 64 + ch];
        mx = fmaxf(mx, pb_max[b * 64 + ch]);
    }
    sa4[part][ch] = s; sm4[part][ch] = mx;
    __syncthreads();
    if (t < 64) {
        p2_sum[blockIdx.x * 64 + t] = sa4[0][t] + sa4[1][t] + sa4[2][t] + sa4[3][t];
        p2_max[blockIdx.x * 64 + t] =
            fmaxf(fmaxf(sm4[0][t], sm4[1][t]), fmaxf(sm4[2][t], sm4[3][t]));
    }
}

// ---------------- head ----------------
__global__ __launch_bounds__(256) void k_head(
    const float* __restrict__ p2_sum, const float* __restrict__ p2_max,
    const float* __restrict__ Wl, const float* __restrict__ bl, float* __restrict__ out) {
    __shared__ float sa4[4][64], sm4[4][64];
    __shared__ float sa[64], sm[64], emb[64];
    int t = threadIdx.x;
    int ch = t & 63, part = t >> 6;
    float s = 0.f, mx = 0.f;
    for (int b = part; b < NB2; b += 4) {
        s += p2_sum[b * 64 + ch];
        mx = fmaxf(mx, p2_max[b * 64 + ch]);
    }
    sa4[part][ch] = s; sm4[part][ch] = mx;
    __syncthreads();
    if (t < 64) {
        sa[t] = sa4[0][t] + sa4[1][t] + sa4[2][t] + sa4[3][t];
        sm[t] = fmaxf(fmaxf(sm4[0][t], sm4[1][t]), fmaxf(sm4[2][t], sm4[3][t]));
    }
    __syncthreads();
    if (t < 64) {
        if (t < 32) {
            emb[t] = (sa[2 * t] + sa[2 * t + 1]) * (0.5f / (float)N_NODES);
        } else {
            int i = t - 32;
            emb[t] = fmaxf(sm[2 * i], sm[2 * i + 1]);
        }
    }
    __syncthreads();
    if (t < 64) {
        float acc = bl[t];
        for (int k = 0; k < 64; ++k) acc = fmaf(emb[k], Wl[k * 64 + t], acc);
        out[t] = acc;
    }
}

extern "C" void kernel_launch(void* const* d_in, const int* in_sizes, int n_in,
                              void* d_out, int out_size, void* d_ws, size_t ws_size,
                              hipStream_t stream) {
    const float* x     = (const float*)d_in[0];
    const float* eattr = (const float*)d_in[1];
    const int*   ei    = (const int*)d_in[2];
    const float* Wn    = (const float*)d_in[3];
    const float* bn    = (const float*)d_in[4];
    const float* We    = (const float*)d_in[5];
    const float* be    = (const float*)d_in[6];
    const float* t     = (const float*)d_in[7];
    const float* W1    = (const float*)d_in[8];
    const float* b1    = (const float*)d_in[9];
    const float* lg    = (const float*)d_in[10];
    const float* lb    = (const float*)d_in[11];
    const float* W2    = (const float*)d_in[12];
    const float* b2    = (const float*)d_in[13];
    const float* ng    = (const float*)d_in[14];
    const float* nb    = (const float*)d_in[15];
    const float* Wl    = (const float*)d_in[16];
    const float* bl    = (const float*)d_in[17];
    float* out = (float*)d_out;

    char* p = (char*)d_ws;
    unsigned short* hb   = (unsigned short*)p; p += (size_t)N_NODES * 64 * 2;
    unsigned short* zb   = (unsigned short*)p; p += (size_t)N_NODES * 64 * 2;
    unsigned short* aggb = (unsigned short*)p; p += (size_t)N_NODES * 64 * 2;
    unsigned int* s_pack = (unsigned int*)p; p += (size_t)N_EDGES * 4;
    int* cnt    = (int*)p;  p += (size_t)(N_NODES + 4) * 4;
    int* offs   = (int*)p;  p += (size_t)(N_NODES + 4) * 4;
    int* inc    = (int*)p;  p += (size_t)(N_NODES + 4) * 4;
    int* bsum   = (int*)p;  p += (size_t)256 * 4;
    float* pb_sum = (float*)p; p += (size_t)NB_F * 64 * 4;
    float* pb_max = (float*)p; p += (size_t)NB_F * 64 * 4;
    float* p2_sum = (float*)p; p += (size_t)NB2 * 64 * 4;
    float* p2_max = (float*)p; p += (size_t)NB2 * 64 * 4;
    unsigned short* w1p = (unsigned short*)p; p += (size_t)3 * 8192 * 2;
    unsigned short* w2p = (unsigned short*)p; p += (size_t)3 * 8192 * 2;
    int* rank = (int*)p;    p += (size_t)N_EDGES * 4;

    hipMemsetAsync(cnt, 0, (N_NODES + 1) * sizeof(int), stream);

    k_node_encode<<<(N_NODES + 3) / 4, 256, 0, stream>>>(x, Wn, bn, zb);
    k_wprep<<<(3 * 8192 + 255) / 256, 256, 0, stream>>>(W1, W2, w1p, w2p);
    k_hist_rank<<<(N_EDGES + 255) / 256, 256, 0, stream>>>(ei, cnt, rank);
    k_scan1<<<SCAN_NB, 256, 0, stream>>>(cnt, inc, bsum);
    k_scan2<<<1, 256, 0, stream>>>(bsum);
    k_scan3<<<SCAN_NB, 256, 0, stream>>>(inc, cnt, bsum, offs);
    k_scatter<<<(N_EDGES + 255) / 256, 256, 0, stream>>>(ei, eattr, offs, rank, s_pack);

    // layer 0
    k_agg<<<(N_NODES + 3) / 4, 256, 0, stream>>>(zb, offs, s_pack, We, be, t, 0, aggb);
    k_mlp<<<NB_F, 256, 0, stream>>>(aggb, zb, hb, w1p, w2p, b1, lg, lb, b2,
                                    ng + 64, nb + 64, 0, pb_sum, pb_max);
    // layer 1
    k_agg<<<(N_NODES + 3) / 4, 256, 0, stream>>>(zb, offs, s_pack, We, be, t, 1, aggb);
    k_mlp<<<NB_F, 256, 0, stream>>>(aggb, zb, hb, w1p + 8192, w2p + 8192,
                                    b1 + 128, lg + 128, lb + 128, b2 + 64,
                                    ng + 128, nb + 128, 1, pb_sum, pb_max);
    // layer 2
    k_agg<<<(N_NODES + 3) / 4, 256, 0, stream>>>(zb, offs, s_pack, We, be, t, 2, aggb);
    k_mlp<<<NB_F, 256, 0, stream>>>(aggb, zb, hb, w1p + 2 * 8192, w2p + 2 * 8192,
                                    b1 + 2 * 128, lg + 2 * 128, lb + 2 * 128, b2 + 2 * 64,
                                    ng, nb, 2, pb_sum, pb_max);

    k_red<<<NB2, 256, 0, stream>>>(pb_sum, pb_max, p2_sum, p2_max);
    k_head<<<1, 256, 0, stream>>>(p2_sum, p2_max, Wl, bl, out);
}

// Round 17
// 370.465 us; speedup vs baseline: 1.0025x; 1.0025x over previous
//
#include <hip/hip_runtime.h>
#include <math.h>

#define N_NODES 50000
#define N_EDGES 1000000
#define HID 64
#define SCAN_NB ((N_NODES + 1 + 255) / 256)
#define N_TILES (N_NODES / 16)          // 3125
#define NB_F ((N_TILES + 3) / 4)        // 782 mlp blocks (4 waves each)
#define NB2 64                          // stage-2 reduction blocks
#define VB_S 72                         // vb row stride (ushorts) — breaks 16-way bank conflict
#define UB_S 136                        // ub row stride (ushorts) — breaks 16-way bank conflict
static_assert(N_NODES % 16 == 0, "tile math");
static_assert(N_NODES <= 65536, "src must fit in 16 bits");

typedef __attribute__((ext_vector_type(8))) short short8;   // 8 bf16 = 4 VGPRs
typedef __attribute__((ext_vector_type(4))) float f32x4;

__device__ __forceinline__ unsigned short f2bf(float x) {   // RNE float->bf16
    unsigned u = __float_as_uint(x);
    u += 0x7FFFu + ((u >> 16) & 1u);
    return (unsigned short)(u >> 16);
}
__device__ __forceinline__ float bfbits_hi(unsigned pk) {   // high-16 bf16 -> f32
    return __uint_as_float(pk & 0xFFFF0000u);
}
__device__ __forceinline__ float bf2f(unsigned short v) {
    return __uint_as_float(((unsigned)v) << 16);
}
// packed bf16 pair add with RNE re-round
__device__ __forceinline__ unsigned addpk(unsigned a, unsigned b) {
    float lo = __uint_as_float(a << 16) + __uint_as_float(b << 16);
    float hi = __uint_as_float(a & 0xFFFF0000u) + __uint_as_float(b & 0xFFFF0000u);
    return (unsigned)f2bf(lo) | ((unsigned)f2bf(hi) << 16);
}

// ---------------- node encoder: zb = bf16(x @ W_node + b_node) ----------------
__global__ __launch_bounds__(256) void k_node_encode(
    const float* __restrict__ x, const float* __restrict__ Wn,
    const float* __restrict__ bn, unsigned short* __restrict__ zb) {
    int n = blockIdx.x * 4 + (threadIdx.x >> 6);
    int c = threadIdx.x & 63;
    if (n >= N_NODES) return;
    float acc = bn[c];
    const float* xr = x + n * 16;
    #pragma unroll
    for (int k = 0; k < 16; ++k) acc = fmaf(xr[k], Wn[k * 64 + c], acc);
    zb[n * 64 + c] = f2bf(acc);
}

// ---------------- weight prep: pack W1/W2 (3 layers) into bf16 fragment order ----------------
__global__ __launch_bounds__(256) void k_wprep(
    const float* __restrict__ W1, const float* __restrict__ W2,
    unsigned short* __restrict__ w1p, unsigned short* __restrict__ w2p) {
    int i = blockIdx.x * 256 + threadIdx.x;
    if (i >= 3 * 8192) return;
    int L = i >> 13, r = i & 8191;
    int j = r & 7, lane = (r >> 3) & 63;
    int quad = lane >> 4, col = lane & 15;
    {
        int st = r >> 9;                 // s=st>>3 (2), t=st&7 (8)
        int s = st >> 3, t = st & 7;
        w1p[i] = f2bf(W1[L * 8192 + (s * 32 + quad * 8 + j) * 128 + t * 16 + col]);
    }
    {
        int ft = r >> 9;                 // s=ft>>2 (4), t=ft&3 (4)
        int s = ft >> 2, t = ft & 3;
        w2p[i] = f2bf(W2[L * 8192 + (s * 32 + quad * 8 + j) * 64 + t * 16 + col]);
    }
}

// ---------------- edge CSR build ----------------
__global__ __launch_bounds__(256) void k_hist_rank(const int* __restrict__ ei,
                                                   int* __restrict__ cnt, int* __restrict__ rank) {
    int i = blockIdx.x * blockDim.x + threadIdx.x;
    if (i >= N_EDGES) return;
    rank[i] = atomicAdd(&cnt[ei[N_EDGES + i]], 1);
}

__global__ __launch_bounds__(256) void k_scan1(const int* __restrict__ cnt,
                                               int* __restrict__ inc, int* __restrict__ bsum) {
    __shared__ int sh[256];
    int gi = blockIdx.x * 256 + threadIdx.x;
    int v = (gi < N_NODES + 1) ? cnt[gi] : 0;
    sh[threadIdx.x] = v;
    __syncthreads();
    #pragma unroll
    for (int d = 1; d < 256; d <<= 1) {
        int t = (threadIdx.x >= d) ? sh[threadIdx.x - d] : 0;
        __syncthreads();
        sh[threadIdx.x] += t;
        __syncthreads();
    }
    if (gi < N_NODES + 1) inc[gi] = sh[threadIdx.x];
    if (threadIdx.x == 255) bsum[blockIdx.x] = sh[255];
}

__global__ __launch_bounds__(256) void k_scan2(int* __restrict__ bsum) {
    __shared__ int sh[256];
    int t = threadIdx.x;
    sh[t] = (t < SCAN_NB) ? bsum[t] : 0;
    __syncthreads();
    #pragma unroll
    for (int d = 1; d < 256; d <<= 1) {
        int v = (t >= d) ? sh[t - d] : 0;
        __syncthreads();
        sh[t] += v;
        __syncthreads();
    }
    if (t < SCAN_NB) bsum[t] = (t == 0) ? 0 : sh[t - 1];
}

__global__ __launch_bounds__(256) void k_scan3(const int* __restrict__ inc,
                                               const int* __restrict__ cnt,
                                               const int* __restrict__ bsum,
                                               int* __restrict__ offs) {
    int gi = blockIdx.x * 256 + threadIdx.x;
    if (gi < N_NODES + 1) offs[gi] = bsum[blockIdx.x] + inc[gi] - cnt[gi];
}

__global__ __launch_bounds__(256) void k_scatter(
    const int* __restrict__ ei, const float* __restrict__ eattr,
    const int* __restrict__ offs, const int* __restrict__ rank,
    unsigned int* __restrict__ s_pack) {
    int i = blockIdx.x * blockDim.x + threadIdx.x;
    if (i >= N_EDGES) return;
    int d = ei[N_EDGES + i];
    int p = offs[d] + rank[i];
    unsigned pk = ((unsigned)f2bf(eattr[i]) << 16) | (unsigned)(ei[i] & 0xFFFF);
    s_pack[p] = pk;
}

// ---------------- softmax aggregation (shift-free), one wave/node, 8-edge ILP ----------------
__global__ __launch_bounds__(256) void k_agg(
    const unsigned short* __restrict__ zb, const int* __restrict__ offs,
    const unsigned int* __restrict__ s_pack,
    const float* __restrict__ We, const float* __restrict__ be,
    const float* __restrict__ t, int layer, unsigned short* __restrict__ aggb) {
    int wid = (blockIdx.x * blockDim.x + threadIdx.x) >> 6;
    int lane = threadIdx.x & 63;
    if (wid >= N_NODES) return;
    int beg = offs[wid], end = offs[wid + 1];
    float we = We[lane], bev = be[lane];
    float tl = t[layer];
    float s = 0.f, num = 0.f;
    int i = beg;
    for (; i + 7 < end; i += 8) {
        unsigned pk[8];
        #pragma unroll
        for (int j = 0; j < 8; ++j) pk[j] = s_pack[i + j];
        float zv[8];
        #pragma unroll
        for (int j = 0; j < 8; ++j) zv[j] = bf2f(zb[(pk[j] & 0xFFFFu) * 64 + lane]);
        float acc_s = 0.f, acc_n = 0.f;
        #pragma unroll
        for (int j = 0; j < 8; ++j) {
            float msg = fmaxf(zv[j] + fmaf(bfbits_hi(pk[j]), we, bev), 0.f) + 1e-7f;
            float p = __expf(msg * tl);
            acc_s += p;
            acc_n = fmaf(p, msg, acc_n);
        }
        s += acc_s;
        num += acc_n;
    }
    for (; i < end; ++i) {
        unsigned pk = s_pack[i];
        float zz = bf2f(zb[(pk & 0xFFFFu) * 64 + lane]);
        float msg = fmaxf(zz + fmaf(bfbits_hi(pk), we, bev), 0.f) + 1e-7f;
        float p = __expf(msg * tl);
        s += p;
        num = fmaf(p, msg, num);
    }
    aggb[wid * 64 + lane] = f2bf(num / (s + 1e-16f));
}

// ---------------- MFMA MLP + fused epilogue (padded LDS, conflict-free) ----------------
// mode 0: layer0 — no residual, write hb, zb <- relu(LN(h, ng, nb)) in place
// mode 1: layer1 — residual,    write hb, zb <- relu(LN(h, ng, nb)) in place
// mode 2: layer2 — residual, no hb write, pool partials with ng/nb
__global__ __launch_bounds__(256) void k_mlp(
    const unsigned short* __restrict__ aggb, unsigned short* __restrict__ zb,
    unsigned short* __restrict__ hb,
    const unsigned short* __restrict__ w1p, const unsigned short* __restrict__ w2p,
    const float* __restrict__ b1,
    const float* __restrict__ g1, const float* __restrict__ be1,
    const float* __restrict__ b2,
    const float* __restrict__ ng, const float* __restrict__ nb, int mode,
    float* __restrict__ pb_sum, float* __restrict__ pb_max) {
    __shared__ unsigned short vbuf[4][16 * VB_S];
    __shared__ unsigned short ubuf[4][16 * UB_S];
    __shared__ float lssum[4][4][16], lsmax[4][4][16];
    int lane = threadIdx.x & 63;
    int wave = threadIdx.x >> 6;
    int col = lane & 15, quad = lane >> 4;
    unsigned short* vb = vbuf[wave];
    unsigned short* ub = ubuf[wave];

    // weight fragments: coalesced dwordx4 loads from packed, L2-hot buffers
    short8 w1f[2][8];
    #pragma unroll
    for (int s = 0; s < 2; ++s)
        #pragma unroll
        for (int t = 0; t < 8; ++t)
            w1f[s][t] = *(const short8*)&w1p[(((s * 8 + t) * 64) + lane) * 8];
    short8 w2f[4][4];
    #pragma unroll
    for (int s = 0; s < 4; ++s)
        #pragma unroll
        for (int t = 0; t < 4; ++t)
            w2f[s][t] = *(const short8*)&w2p[(((s * 4 + t) * 64) + lane) * 8];

    float b1f[8], g1f[8], e1f[8];
    #pragma unroll
    for (int t = 0; t < 8; ++t) {
        int ch = t * 16 + col;
        b1f[t] = b1[ch]; g1f[t] = g1[ch]; e1f[t] = be1[ch];
    }
    float b2f_[4], ngf[4], nbf[4];
    #pragma unroll
    for (int t = 0; t < 4; ++t) {
        b2f_[t] = b2[t * 16 + col];
        ngf[t] = ng[t * 16 + col];
        nbf[t] = nb[t * 16 + col];
    }

    float psum[4] = {0.f, 0.f, 0.f, 0.f};
    float pmax[4] = {0.f, 0.f, 0.f, 0.f};
    int nd = lane >> 2;
    int cg = (lane & 3) * 16;
    int tile = blockIdx.x * 4 + wave;

    if (tile < N_TILES) {
        int n0 = tile * 16;
        const uint4* ap = (const uint4*)(aggb + (size_t)(n0 + nd) * 64 + cg);
        const uint4* zp = (const uint4*)(zb + (size_t)(n0 + nd) * 64 + cg);
        uint4 a0 = ap[0], a1 = ap[1], z0 = zp[0], z1 = zp[1];
        uint4 r0, r1;
        r0.x = addpk(a0.x, z0.x); r0.y = addpk(a0.y, z0.y);
        r0.z = addpk(a0.z, z0.z); r0.w = addpk(a0.w, z0.w);
        r1.x = addpk(a1.x, z1.x); r1.y = addpk(a1.y, z1.y);
        r1.z = addpk(a1.z, z1.z); r1.w = addpk(a1.w, z1.w);
        uint4* vdst = (uint4*)&vb[nd * VB_S + cg];
        vdst[0] = r0;
        vdst[1] = r1;

        // GEMM1 (A-reads now 2-way/bank = free)
        short8 af0 = *(const short8*)&vb[col * VB_S + quad * 8];
        short8 af1 = *(const short8*)&vb[col * VB_S + 32 + quad * 8];
        f32x4 au[8];
        #pragma unroll
        for (int t = 0; t < 8; ++t) {
            f32x4 c = {0.f, 0.f, 0.f, 0.f};
            c = __builtin_amdgcn_mfma_f32_16x16x32_bf16(af0, w1f[0][t], c, 0, 0, 0);
            c = __builtin_amdgcn_mfma_f32_16x16x32_bf16(af1, w1f[1][t], c, 0, 0, 0);
            au[t] = c;
        }
        // LN(128)+relu -> ub
        #pragma unroll
        for (int r = 0; r < 4; ++r) {
            float sx = 0.f, sq = 0.f;
            #pragma unroll
            for (int t = 0; t < 8; ++t) {
                float v = au[t][r] + b1f[t];
                sx += v; sq += v * v;
            }
            #pragma unroll
            for (int mask = 1; mask < 16; mask <<= 1) {
                sx += __shfl_xor(sx, mask, 64);
                sq += __shfl_xor(sq, mask, 64);
            }
            float mu = sx * (1.f / 128.f);
            float var = sq * (1.f / 128.f) - mu * mu;
            float rs = rsqrtf(var + 1e-5f);
            int row = quad * 4 + r;
            #pragma unroll
            for (int t = 0; t < 8; ++t) {
                float v = au[t][r] + b1f[t];
                float y = fmaxf(fmaf((v - mu) * rs, g1f[t], e1f[t]), 0.f);
                ub[row * UB_S + t * 16 + col] = f2bf(y);
            }
        }
        // GEMM2
        f32x4 oc[4];
        #pragma unroll
        for (int t = 0; t < 4; ++t) oc[t] = (f32x4){0.f, 0.f, 0.f, 0.f};
        #pragma unroll
        for (int s = 0; s < 4; ++s) {
            short8 a = *(const short8*)&ub[col * UB_S + s * 32 + quad * 8];
            #pragma unroll
            for (int t = 0; t < 4; ++t)
                oc[t] = __builtin_amdgcn_mfma_f32_16x16x32_bf16(a, w2f[s][t], oc[t], 0, 0, 0);
        }
        // epilogue
        #pragma unroll
        for (int r = 0; r < 4; ++r) {
            int n = n0 + quad * 4 + r;
            float val[4];
            #pragma unroll
            for (int t = 0; t < 4; ++t) {
                val[t] = oc[t][r] + b2f_[t];
                if (mode >= 1) val[t] += bf2f(hb[(size_t)n * 64 + t * 16 + col]);
            }
            if (mode <= 1) {
                #pragma unroll
                for (int t = 0; t < 4; ++t) hb[(size_t)n * 64 + t * 16 + col] = f2bf(val[t]);
            }
            float sx = 0.f, sq = 0.f;
            #pragma unroll
            for (int t = 0; t < 4; ++t) { sx += val[t]; sq += val[t] * val[t]; }
            #pragma unroll
            for (int mask = 1; mask < 16; mask <<= 1) {
                sx += __shfl_xor(sx, mask, 64);
                sq += __shfl_xor(sq, mask, 64);
            }
            float mu = sx * (1.f / 64.f);
            float var = sq * (1.f / 64.f) - mu * mu;
            float rs = rsqrtf(var + 1e-5f);
            #pragma unroll
            for (int t = 0; t < 4; ++t) {
                float y = fmaxf(fmaf((val[t] - mu) * rs, ngf[t], nbf[t]), 0.f);
                if (mode <= 1) {
                    zb[(size_t)n * 64 + t * 16 + col] = f2bf(y);
                } else {
                    psum[t] += y;
                    pmax[t] = fmaxf(pmax[t], y);
                }
            }
        }
    }
    if (mode == 2) {
        #pragma unroll
        for (int t = 0; t < 4; ++t) {
            psum[t] += __shfl_xor(psum[t], 16, 64);
            psum[t] += __shfl_xor(psum[t], 32, 64);
            pmax[t] = fmaxf(pmax[t], __shfl_xor(pmax[t], 16, 64));
            pmax[t] = fmaxf(pmax[t], __shfl_xor(pmax[t], 32, 64));
        }
        if (quad == 0) {
            #pragma unroll
            for (int t = 0; t < 4; ++t) {
                lssum[wave][t][col] = psum[t];
                lsmax[wave][t][col] = pmax[t];
            }
        }
        __syncthreads();
        if (wave == 0) {
            int t = lane >> 4, c = lane & 15;
            float s = lssum[0][t][c] + lssum[1][t][c] + lssum[2][t][c] + lssum[3][t][c];
            float mx = fmaxf(fmaxf(lsmax[0][t][c], lsmax[1][t][c]),
                             fmaxf(lsmax[2][t][c], lsmax[3][t][c]));
            pb_sum[blockIdx.x * 64 + lane] = s;
            pb_max[blockIdx.x * 64 + lane] = mx;
        }
    }
}

// ---------------- stage-2 reduce: 782 partial rows -> 64 rows ----------------
__global__ __launch_bounds__(256) void k_red(
    const float* __restrict__ pb_sum, const float* __restrict__ pb_max,
    float* __restrict__ p2_sum, float* __restrict__ p2_max) {
    __shared__ float sa4[4][64], sm4[4][64];
    int t = threadIdx.x;
    int ch = t & 63, part = t >> 6;
    float s = 0.f, mx = 0.f;
    for (int b = blockIdx.x + NB2 * part; b < NB_F; b += NB2 * 4) {
        s += pb_sum[b * 64 + ch];
        mx = fmaxf(mx, pb_max[b * 64 + ch]);
    }
    sa4[part][ch] = s; sm4[part][ch] = mx;
    __syncthreads();
    if (t < 64) {
        p2_sum[blockIdx.x * 64 + t] = sa4[0][t] + sa4[1][t] + sa4[2][t] + sa4[3][t];
        p2_max[blockIdx.x * 64 + t] =
            fmaxf(fmaxf(sm4[0][t], sm4[1][t]), fmaxf(sm4[2][t], sm4[3][t]));
    }
}

// ---------------- head ----------------
__global__ __launch_bounds__(256) void k_head(
    const float* __restrict__ p2_sum, const float* __restrict__ p2_max,
    const float* __restrict__ Wl, const float* __restrict__ bl, float* __restrict__ out) {
    __shared__ float sa4[4][64], sm4[4][64];
    __shared__ float sa[64], sm[64], emb[64];
    int t = threadIdx.x;
    int ch = t & 63, part = t >> 6;
    float s = 0.f, mx = 0.f;
    for (int b = part; b < NB2; b += 4) {
        s += p2_sum[b * 64 + ch];
        mx = fmaxf(mx, p2_max[b * 64 + ch]);
    }
    sa4[part][ch] = s; sm4[part][ch] = mx;
    __syncthreads();
    if (t < 64) {
        sa[t] = sa4[0][t] + sa4[1][t] + sa4[2][t] + sa4[3][t];
        sm[t] = fmaxf(fmaxf(sm4[0][t], sm4[1][t]), fmaxf(sm4[2][t], sm4[3][t]));
    }
    __syncthreads();
    if (t < 64) {
        if (t < 32) {
            emb[t] = (sa[2 * t] + sa[2 * t + 1]) * (0.5f / (float)N_NODES);
        } else {
            int i = t - 32;
            emb[t] = fmaxf(sm[2 * i], sm[2 * i + 1]);
        }
    }
    __syncthreads();
    if (t < 64) {
        float acc = bl[t];
        for (int k = 0; k < 64; ++k) acc = fmaf(emb[k], Wl[k * 64 + t], acc);
        out[t] = acc;
    }
}

extern "C" void kernel_launch(void* const* d_in, const int* in_sizes, int n_in,
                              void* d_out, int out_size, void* d_ws, size_t ws_size,
                              hipStream_t stream) {
    const float* x     = (const float*)d_in[0];
    const float* eattr = (const float*)d_in[1];
    const int*   ei    = (const int*)d_in[2];
    const float* Wn    = (const float*)d_in[3];
    const float* bn    = (const float*)d_in[4];
    const float* We    = (const float*)d_in[5];
    const float* be    = (const float*)d_in[6];
    const float* t     = (const float*)d_in[7];
    const float* W1    = (const float*)d_in[8];
    const float* b1    = (const float*)d_in[9];
    const float* lg    = (const float*)d_in[10];
    const float* lb    = (const float*)d_in[11];
    const float* W2    = (const float*)d_in[12];
    const float* b2    = (const float*)d_in[13];
    const float* ng    = (const float*)d_in[14];
    const float* nb    = (const float*)d_in[15];
    const float* Wl    = (const float*)d_in[16];
    const float* bl    = (const float*)d_in[17];
    float* out = (float*)d_out;

    char* p = (char*)d_ws;
    unsigned short* hb   = (unsigned short*)p; p += (size_t)N_NODES * 64 * 2;
    unsigned short* zb   = (unsigned short*)p; p += (size_t)N_NODES * 64 * 2;
    unsigned short* aggb = (unsigned short*)p; p += (size_t)N_NODES * 64 * 2;
    unsigned int* s_pack = (unsigned int*)p; p += (size_t)N_EDGES * 4;
    int* cnt    = (int*)p;  p += (size_t)(N_NODES + 4) * 4;
    int* offs   = (int*)p;  p += (size_t)(N_NODES + 4) * 4;
    int* inc    = (int*)p;  p += (size_t)(N_NODES + 4) * 4;
    int* bsum   = (int*)p;  p += (size_t)256 * 4;
    float* pb_sum = (float*)p; p += (size_t)NB_F * 64 * 4;
    float* pb_max = (float*)p; p += (size_t)NB_F * 64 * 4;
    float* p2_sum = (float*)p; p += (size_t)NB2 * 64 * 4;
    float* p2_max = (float*)p; p += (size_t)NB2 * 64 * 4;
    unsigned short* w1p = (unsigned short*)p; p += (size_t)3 * 8192 * 2;
    unsigned short* w2p = (unsigned short*)p; p += (size_t)3 * 8192 * 2;
    int* rank = (int*)p;    p += (size_t)N_EDGES * 4;

    hipMemsetAsync(cnt, 0, (N_NODES + 1) * sizeof(int), stream);

    k_node_encode<<<(N_NODES + 3) / 4, 256, 0, stream>>>(x, Wn, bn, zb);
    k_wprep<<<(3 * 8192 + 255) / 256, 256, 0, stream>>>(W1, W2, w1p, w2p);
    k_hist_rank<<<(N_EDGES + 255) / 256, 256, 0, stream>>>(ei, cnt, rank);
    k_scan1<<<SCAN_NB, 256, 0, stream>>>(cnt, inc, bsum);
    k_scan2<<<1, 256, 0, stream>>>(bsum);
    k_scan3<<<SCAN_NB, 256, 0, stream>>>(inc, cnt, bsum, offs);
    k_scatter<<<(N_EDGES + 255) / 256, 256, 0, stream>>>(ei, eattr, offs, rank, s_pack);

    // layer 0
    k_agg<<<(N_NODES + 3) / 4, 256, 0, stream>>>(zb, offs, s_pack, We, be, t, 0, aggb);
    k_mlp<<<NB_F, 256, 0, stream>>>(aggb, zb, hb, w1p, w2p, b1, lg, lb, b2,
                                    ng + 64, nb + 64, 0, pb_sum, pb_max);
    // layer 1
    k_agg<<<(N_NODES + 3) / 4, 256, 0, stream>>>(zb, offs, s_pack, We, be, t, 1, aggb);
    k_mlp<<<NB_F, 256, 0, stream>>>(aggb, zb, hb, w1p + 8192, w2p + 8192,
                                    b1 + 128, lg + 128, lb + 128, b2 + 64,
                                    ng + 128, nb + 128, 1, pb_sum, pb_max);
    // layer 2
    k_agg<<<(N_NODES + 3) / 4, 256, 0, stream>>>(zb, offs, s_pack, We, be, t, 2, aggb);
    k_mlp<<<NB_F, 256, 0, stream>>>(aggb, zb, hb, w1p + 2 * 8192, w2p + 2 * 8192,
                                    b1 + 2 * 128, lg + 2 * 128, lb + 2 * 128, b2 + 2 * 64,
                                    ng, nb, 2, pb_sum, pb_max);

    k_red<<<NB2, 256, 0, stream>>>(pb_sum, pb_max, p2_sum, p2_max);
    k_head<<<1, 256, 0, stream>>>(p2_sum, p2_max, Wl, bl, out);
}

// Round 18
// 356.165 us; speedup vs baseline: 1.0427x; 1.0401x over previous
//
#include <hip/hip_runtime.h>
#include <math.h>

#define N_NODES 50000
#define N_EDGES 1000000
#define HID 64
#define SCAN_NB ((N_NODES + 1 + 255) / 256)
#define N_TILES (N_NODES / 16)          // 3125
#define NB_MLP 512                      // mlp blocks (4 waves each, grid-stride)
#define NB2 64                          // stage-2 reduction blocks
#define VB_S 72                         // vb row stride (ushorts)
#define UB_S 136                        // ub row stride (ushorts)
static_assert(N_NODES % 16 == 0, "tile math");
static_assert(N_NODES <= 65536, "src must fit in 16 bits");

typedef __attribute__((ext_vector_type(8))) short short8;   // 8 bf16 = 4 VGPRs
typedef __attribute__((ext_vector_type(4))) float f32x4;

__device__ __forceinline__ unsigned short f2bf(float x) {   // RNE float->bf16
    unsigned u = __float_as_uint(x);
    u += 0x7FFFu + ((u >> 16) & 1u);
    return (unsigned short)(u >> 16);
}
__device__ __forceinline__ float bfbits_hi(unsigned pk) {
    return __uint_as_float(pk & 0xFFFF0000u);
}
__device__ __forceinline__ float bf2f(unsigned short v) {
    return __uint_as_float(((unsigned)v) << 16);
}
__device__ __forceinline__ unsigned addpk(unsigned a, unsigned b) {
    float lo = __uint_as_float(a << 16) + __uint_as_float(b << 16);
    float hi = __uint_as_float(a & 0xFFFF0000u) + __uint_as_float(b & 0xFFFF0000u);
    return (unsigned)f2bf(lo) | ((unsigned)f2bf(hi) << 16);
}

// ---------------- node encoder: zb = bf16(x @ W_node + b_node) ----------------
__global__ __launch_bounds__(256) void k_node_encode(
    const float* __restrict__ x, const float* __restrict__ Wn,
    const float* __restrict__ bn, unsigned short* __restrict__ zb) {
    int n = blockIdx.x * 4 + (threadIdx.x >> 6);
    int c = threadIdx.x & 63;
    if (n >= N_NODES) return;
    float acc = bn[c];
    const float* xr = x + n * 16;
    #pragma unroll
    for (int k = 0; k < 16; ++k) acc = fmaf(xr[k], Wn[k * 64 + c], acc);
    zb[n * 64 + c] = f2bf(acc);
}

// ---------------- weight prep: pack W1/W2 (3 layers) into bf16 fragment order ----------------
__global__ __launch_bounds__(256) void k_wprep(
    const float* __restrict__ W1, const float* __restrict__ W2,
    unsigned short* __restrict__ w1p, unsigned short* __restrict__ w2p) {
    int i = blockIdx.x * 256 + threadIdx.x;
    if (i >= 3 * 8192) return;
    int L = i >> 13, r = i & 8191;
    int j = r & 7, lane = (r >> 3) & 63;
    int quad = lane >> 4, col = lane & 15;
    {
        int st = r >> 9;                 // s=st>>3 (2), t=st&7 (8)
        int s = st >> 3, t = st & 7;
        w1p[i] = f2bf(W1[L * 8192 + (s * 32 + quad * 8 + j) * 128 + t * 16 + col]);
    }
    {
        int ft = r >> 9;                 // s=ft>>2 (4), t=ft&3 (4)
        int s = ft >> 2, t = ft & 3;
        w2p[i] = f2bf(W2[L * 8192 + (s * 32 + quad * 8 + j) * 64 + t * 16 + col]);
    }
}

// ---------------- edge CSR build ----------------
__global__ __launch_bounds__(256) void k_hist_rank(const int* __restrict__ ei,
                                                   int* __restrict__ cnt, int* __restrict__ rank) {
    int i = blockIdx.x * blockDim.x + threadIdx.x;
    if (i >= N_EDGES) return;
    rank[i] = atomicAdd(&cnt[ei[N_EDGES + i]], 1);
}

__global__ __launch_bounds__(256) void k_scan1(const int* __restrict__ cnt,
                                               int* __restrict__ inc, int* __restrict__ bsum) {
    __shared__ int sh[256];
    int gi = blockIdx.x * 256 + threadIdx.x;
    int v = (gi < N_NODES + 1) ? cnt[gi] : 0;
    sh[threadIdx.x] = v;
    __syncthreads();
    #pragma unroll
    for (int d = 1; d < 256; d <<= 1) {
        int t = (threadIdx.x >= d) ? sh[threadIdx.x - d] : 0;
        __syncthreads();
        sh[threadIdx.x] += t;
        __syncthreads();
    }
    if (gi < N_NODES + 1) inc[gi] = sh[threadIdx.x];
    if (threadIdx.x == 255) bsum[blockIdx.x] = sh[255];
}

__global__ __launch_bounds__(256) void k_scan2(int* __restrict__ bsum) {
    __shared__ int sh[256];
    int t = threadIdx.x;
    sh[t] = (t < SCAN_NB) ? bsum[t] : 0;
    __syncthreads();
    #pragma unroll
    for (int d = 1; d < 256; d <<= 1) {
        int v = (t >= d) ? sh[t - d] : 0;
        __syncthreads();
        sh[t] += v;
        __syncthreads();
    }
    if (t < SCAN_NB) bsum[t] = (t == 0) ? 0 : sh[t - 1];
}

__global__ __launch_bounds__(256) void k_scan3(const int* __restrict__ inc,
                                               const int* __restrict__ cnt,
                                               const int* __restrict__ bsum,
                                               int* __restrict__ offs) {
    int gi = blockIdx.x * 256 + threadIdx.x;
    if (gi < N_NODES + 1) offs[gi] = bsum[blockIdx.x] + inc[gi] - cnt[gi];
}

__global__ __launch_bounds__(256) void k_scatter(
    const int* __restrict__ ei, const float* __restrict__ eattr,
    const int* __restrict__ offs, const int* __restrict__ rank,
    unsigned int* __restrict__ s_pack) {
    int i = blockIdx.x * blockDim.x + threadIdx.x;
    if (i >= N_EDGES) return;
    int d = ei[N_EDGES + i];
    int p = offs[d] + rank[i];
    unsigned pk = ((unsigned)f2bf(eattr[i]) << 16) | (unsigned)(ei[i] & 0xFFFF);
    s_pack[p] = pk;
}

// ---------------- softmax aggregation (shift-free), one wave/node, 8-edge ILP ----------------
__global__ __launch_bounds__(256) void k_agg(
    const unsigned short* __restrict__ zb, const int* __restrict__ offs,
    const unsigned int* __restrict__ s_pack,
    const float* __restrict__ We, const float* __restrict__ be,
    const float* __restrict__ t, int layer, unsigned short* __restrict__ aggb) {
    int wid = (blockIdx.x * blockDim.x + threadIdx.x) >> 6;
    int lane = threadIdx.x & 63;
    if (wid >= N_NODES) return;
    int beg = offs[wid], end = offs[wid + 1];
    float we = We[lane], bev = be[lane];
    float tl = t[layer];
    float s = 0.f, num = 0.f;
    int i = beg;
    for (; i + 7 < end; i += 8) {
        unsigned pk[8];
        #pragma unroll
        for (int j = 0; j < 8; ++j) pk[j] = s_pack[i + j];
        float zv[8];
        #pragma unroll
        for (int j = 0; j < 8; ++j) zv[j] = bf2f(zb[(pk[j] & 0xFFFFu) * 64 + lane]);
        float acc_s = 0.f, acc_n = 0.f;
        #pragma unroll
        for (int j = 0; j < 8; ++j) {
            float msg = fmaxf(zv[j] + fmaf(bfbits_hi(pk[j]), we, bev), 0.f) + 1e-7f;
            float p = __expf(msg * tl);
            acc_s += p;
            acc_n = fmaf(p, msg, acc_n);
        }
        s += acc_s;
        num += acc_n;
    }
    for (; i < end; ++i) {
        unsigned pk = s_pack[i];
        float zz = bf2f(zb[(pk & 0xFFFFu) * 64 + lane]);
        float msg = fmaxf(zz + fmaf(bfbits_hi(pk), we, bev), 0.f) + 1e-7f;
        float p = __expf(msg * tl);
        s += p;
        num = fmaf(p, msg, num);
    }
    aggb[wid * 64 + lane] = f2bf(num / (s + 1e-16f));
}

// ---------------- MFMA MLP: block-shared weights in LDS, coalesced epilogue ----------------
// mode 0: layer0 — no residual, write hb, zb <- relu(LN(h, ng, nb)) in place
// mode 1: layer1 — residual,    write hb, zb <- relu(LN(h, ng, nb)) in place
// mode 2: layer2 — residual, no hb write, pool partials with ng/nb
__global__ __launch_bounds__(256) void k_mlp(
    const unsigned short* __restrict__ aggb, unsigned short* __restrict__ zb,
    unsigned short* __restrict__ hb,
    const unsigned short* __restrict__ w1p, const unsigned short* __restrict__ w2p,
    const float* __restrict__ b1,
    const float* __restrict__ g1, const float* __restrict__ be1,
    const float* __restrict__ b2,
    const float* __restrict__ ng, const float* __restrict__ nb, int mode,
    float* __restrict__ pb_sum, float* __restrict__ pb_max) {
    __shared__ unsigned short w1s[8192];            // 16 KB, shared by all 4 waves
    __shared__ unsigned short w2s[8192];            // 16 KB
    __shared__ unsigned short vbuf[4][16 * VB_S];
    __shared__ unsigned short ubuf[4][16 * UB_S];
    __shared__ float lssum[4][4][16], lsmax[4][4][16];
    int lane = threadIdx.x & 63;
    int wave = threadIdx.x >> 6;
    int col = lane & 15, quad = lane >> 4;
    unsigned short* vb = vbuf[wave];
    unsigned short* ub = ubuf[wave];

    // one-time cooperative weight stage: 2048+2048 uint4 over 256 threads
    {
        const uint4* s1 = (const uint4*)w1p;
        const uint4* s2 = (const uint4*)w2p;
        uint4* d1 = (uint4*)w1s;
        uint4* d2 = (uint4*)w2s;
        #pragma unroll
        for (int i = 0; i < 4; ++i) {
            d1[threadIdx.x + i * 256] = s1[threadIdx.x + i * 256];
            d2[threadIdx.x + i * 256] = s2[threadIdx.x + i * 256];
        }
    }
    __syncthreads();

    float b1f[8], g1f[8], e1f[8];
    #pragma unroll
    for (int t = 0; t < 8; ++t) {
        int ch = t * 16 + col;
        b1f[t] = b1[ch]; g1f[t] = g1[ch]; e1f[t] = be1[ch];
    }
    float b2f_[4], ngf[4], nbf[4];
    #pragma unroll
    for (int t = 0; t < 4; ++t) {
        b2f_[t] = b2[t * 16 + col];
        ngf[t] = ng[t * 16 + col];
        nbf[t] = nb[t * 16 + col];
    }

    float psum[4] = {0.f, 0.f, 0.f, 0.f};
    float pmax[4] = {0.f, 0.f, 0.f, 0.f};
    int nd = lane >> 2;
    int cg = (lane & 3) * 16;

    for (int tile = blockIdx.x * 4 + wave; tile < N_TILES; tile += NB_MLP * 4) {
        int n0 = tile * 16;
        // stage v = bf16(aggb + zb) into vb
        const uint4* ap = (const uint4*)(aggb + (size_t)(n0 + nd) * 64 + cg);
        const uint4* zp = (const uint4*)(zb + (size_t)(n0 + nd) * 64 + cg);
        uint4 a0 = ap[0], a1 = ap[1], z0 = zp[0], z1 = zp[1];
        uint4 r0, r1;
        r0.x = addpk(a0.x, z0.x); r0.y = addpk(a0.y, z0.y);
        r0.z = addpk(a0.z, z0.z); r0.w = addpk(a0.w, z0.w);
        r1.x = addpk(a1.x, z1.x); r1.y = addpk(a1.y, z1.y);
        r1.z = addpk(a1.z, z1.z); r1.w = addpk(a1.w, z1.w);
        uint4* vdst = (uint4*)&vb[nd * VB_S + cg];
        vdst[0] = r0;
        vdst[1] = r1;

        // GEMM1 (A from vb, B from w1s)
        short8 af0 = *(const short8*)&vb[col * VB_S + quad * 8];
        short8 af1 = *(const short8*)&vb[col * VB_S + 32 + quad * 8];

        // early: coalesced residual fetch for this tile (overlaps GEMM1 latency)
        uint4 h0, h1;
        if (mode >= 1) {
            const uint4* hp = (const uint4*)(hb + (size_t)(n0 + nd) * 64 + cg);
            h0 = hp[0]; h1 = hp[1];
        }

        f32x4 au[8];
        #pragma unroll
        for (int t = 0; t < 8; ++t) {
            short8 w0 = *(const short8*)&w1s[((0 * 8 + t) * 64 + lane) * 8];
            short8 w1 = *(const short8*)&w1s[((1 * 8 + t) * 64 + lane) * 8];
            f32x4 c = {0.f, 0.f, 0.f, 0.f};
            c = __builtin_amdgcn_mfma_f32_16x16x32_bf16(af0, w0, c, 0, 0, 0);
            c = __builtin_amdgcn_mfma_f32_16x16x32_bf16(af1, w1, c, 0, 0, 0);
            au[t] = c;
        }
        // LN(128)+relu -> ub
        #pragma unroll
        for (int r = 0; r < 4; ++r) {
            float sx = 0.f, sq = 0.f;
            #pragma unroll
            for (int t = 0; t < 8; ++t) {
                float v = au[t][r] + b1f[t];
                sx += v; sq += v * v;
            }
            #pragma unroll
            for (int mask = 1; mask < 16; mask <<= 1) {
                sx += __shfl_xor(sx, mask, 64);
                sq += __shfl_xor(sq, mask, 64);
            }
            float mu = sx * (1.f / 128.f);
            float var = sq * (1.f / 128.f) - mu * mu;
            float rs = rsqrtf(var + 1e-5f);
            int row = quad * 4 + r;
            #pragma unroll
            for (int t = 0; t < 8; ++t) {
                float v = au[t][r] + b1f[t];
                float y = fmaxf(fmaf((v - mu) * rs, g1f[t], e1f[t]), 0.f);
                ub[row * UB_S + t * 16 + col] = f2bf(y);
            }
        }
        // GEMM2 (A from ub, B from w2s)
        f32x4 oc[4];
        #pragma unroll
        for (int t = 0; t < 4; ++t) oc[t] = (f32x4){0.f, 0.f, 0.f, 0.f};
        #pragma unroll
        for (int s = 0; s < 4; ++s) {
            short8 a = *(const short8*)&ub[col * UB_S + s * 32 + quad * 8];
            #pragma unroll
            for (int t = 0; t < 4; ++t) {
                short8 w = *(const short8*)&w2s[((s * 4 + t) * 64 + lane) * 8];
                oc[t] = __builtin_amdgcn_mfma_f32_16x16x32_bf16(a, w, oc[t], 0, 0, 0);
            }
        }
        // stage residual rows into vb (vb free after af reads)
        if (mode >= 1) {
            uint4* hdst = (uint4*)&vb[nd * VB_S + cg];
            hdst[0] = h0;
            hdst[1] = h1;
        }
        // epilogue: bias (+res) -> LN64 -> scatter into LDS, coalesced writeback
        #pragma unroll
        for (int r = 0; r < 4; ++r) {
            int row = quad * 4 + r;
            float val[4];
            #pragma unroll
            for (int t = 0; t < 4; ++t) {
                val[t] = oc[t][r] + b2f_[t];
                if (mode >= 1) val[t] += bf2f(vb[row * VB_S + t * 16 + col]);
            }
            float sx = 0.f, sq = 0.f;
            #pragma unroll
            for (int t = 0; t < 4; ++t) { sx += val[t]; sq += val[t] * val[t]; }
            #pragma unroll
            for (int mask = 1; mask < 16; mask <<= 1) {
                sx += __shfl_xor(sx, mask, 64);
                sq += __shfl_xor(sq, mask, 64);
            }
            float mu = sx * (1.f / 64.f);
            float var = sq * (1.f / 64.f) - mu * mu;
            float rs = rsqrtf(var + 1e-5f);
            #pragma unroll
            for (int t = 0; t < 4; ++t) {
                float y = fmaxf(fmaf((val[t] - mu) * rs, ngf[t], nbf[t]), 0.f);
                if (mode <= 1) {
                    vb[row * VB_S + t * 16 + col] = f2bf(val[t]);   // h
                    ub[row * UB_S + t * 16 + col] = f2bf(y);        // z
                } else {
                    psum[t] += y;
                    pmax[t] = fmaxf(pmax[t], y);
                }
            }
        }
        if (mode <= 1) {
            // coalesced writeback from LDS
            const uint4* hsrc = (const uint4*)&vb[nd * VB_S + cg];
            const uint4* zsrc = (const uint4*)&ub[nd * UB_S + cg];
            uint4* hdst = (uint4*)(hb + (size_t)(n0 + nd) * 64 + cg);
            uint4* zdst = (uint4*)(zb + (size_t)(n0 + nd) * 64 + cg);
            hdst[0] = hsrc[0]; hdst[1] = hsrc[1];
            zdst[0] = zsrc[0]; zdst[1] = zsrc[1];
        }
    }
    if (mode == 2) {
        #pragma unroll
        for (int t = 0; t < 4; ++t) {
            psum[t] += __shfl_xor(psum[t], 16, 64);
            psum[t] += __shfl_xor(psum[t], 32, 64);
            pmax[t] = fmaxf(pmax[t], __shfl_xor(pmax[t], 16, 64));
            pmax[t] = fmaxf(pmax[t], __shfl_xor(pmax[t], 32, 64));
        }
        if (quad == 0) {
            #pragma unroll
            for (int t = 0; t < 4; ++t) {
                lssum[wave][t][col] = psum[t];
                lsmax[wave][t][col] = pmax[t];
            }
        }
        __syncthreads();
        if (wave == 0) {
            int t = lane >> 4, c = lane & 15;
            float s = lssum[0][t][c] + lssum[1][t][c] + lssum[2][t][c] + lssum[3][t][c];
            float mx = fmaxf(fmaxf(lsmax[0][t][c], lsmax[1][t][c]),
                             fmaxf(lsmax[2][t][c], lsmax[3][t][c]));
            pb_sum[blockIdx.x * 64 + lane] = s;
            pb_max[blockIdx.x * 64 + lane] = mx;
        }
    }
}

// ---------------- stage-2 reduce: NB_MLP partial rows -> 64 rows ----------------
__global__ __launch_bounds__(256) void k_red(
    const float* __restrict__ pb_sum, const float* __restrict__ pb_max,
    float* __restrict__ p2_sum, float* __restrict__ p2_max) {
    __shared__ float sa4[4][64], sm4[4][64];
    int t = threadIdx.x;
    int ch = t & 63, part = t >> 6;
    float s = 0.f, mx = 0.f;
    for (int b = blockIdx.x + NB2 * part; b < NB_MLP; b += NB2 * 4) {
        s += pb_sum[b * 64 + ch];
        mx = fmaxf(mx, pb_max[b * 64 + ch]);
    }
    sa4[part][ch] = s; sm4[part][ch] = mx;
    __syncthreads();
    if (t < 64) {
        p2_sum[blockIdx.x * 64 + t] = sa4[0][t] + sa4[1][t] + sa4[2][t] + sa4[3][t];
        p2_max[blockIdx.x * 64 + t] =
            fmaxf(fmaxf(sm4[0][t], sm4[1][t]), fmaxf(sm4[2][t], sm4[3][t]));
    }
}

// ---------------- head ----------------
__global__ __launch_bounds__(256) void k_head(
    const float* __restrict__ p2_sum, const float* __restrict__ p2_max,
    const float* __restrict__ Wl, const float* __restrict__ bl, float* __restrict__ out) {
    __shared__ float sa4[4][64], sm4[4][64];
    __shared__ float sa[64], sm[64], emb[64];
    int t = threadIdx.x;
    int ch = t & 63, part = t >> 6;
    float s = 0.f, mx = 0.f;
    for (int b = part; b < NB2; b += 4) {
        s += p2_sum[b * 64 + ch];
        mx = fmaxf(mx, p2_max[b * 64 + ch]);
    }
    sa4[part][ch] = s; sm4[part][ch] = mx;
    __syncthreads();
    if (t < 64) {
        sa[t] = sa4[0][t] + sa4[1][t] + sa4[2][t] + sa4[3][t];
        sm[t] = fmaxf(fmaxf(sm4[0][t], sm4[1][t]), fmaxf(sm4[2][t], sm4[3][t]));
    }
    __syncthreads();
    if (t < 64) {
        if (t < 32) {
            emb[t] = (sa[2 * t] + sa[2 * t + 1]) * (0.5f / (float)N_NODES);
        } else {
            int i = t - 32;
            emb[t] = fmaxf(sm[2 * i], sm[2 * i + 1]);
        }
    }
    __syncthreads();
    if (t < 64) {
        float acc = bl[t];
        for (int k = 0; k < 64; ++k) acc = fmaf(emb[k], Wl[k * 64 + t], acc);
        out[t] = acc;
    }
}

extern "C" void kernel_launch(void* const* d_in, const int* in_sizes, int n_in,
                              void* d_out, int out_size, void* d_ws, size_t ws_size,
                              hipStream_t stream) {
    const float* x     = (const float*)d_in[0];
    const float* eattr = (const float*)d_in[1];
    const int*   ei    = (const int*)d_in[2];
    const float* Wn    = (const float*)d_in[3];
    const float* bn    = (const float*)d_in[4];
    const float* We    = (const float*)d_in[5];
    const float* be    = (const float*)d_in[6];
    const float* t     = (const float*)d_in[7];
    const float* W1    = (const float*)d_in[8];
    const float* b1    = (const float*)d_in[9];
    const float* lg    = (const float*)d_in[10];
    const float* lb    = (const float*)d_in[11];
    const float* W2    = (const float*)d_in[12];
    const float* b2    = (const float*)d_in[13];
    const float* ng    = (const float*)d_in[14];
    const float* nb    = (const float*)d_in[15];
    const float* Wl    = (const float*)d_in[16];
    const float* bl    = (const float*)d_in[17];
    float* out = (float*)d_out;

    char* p = (char*)d_ws;
    unsigned short* hb   = (unsigned short*)p; p += (size_t)N_NODES * 64 * 2;
    unsigned short* zb   = (unsigned short*)p; p += (size_t)N_NODES * 64 * 2;
    unsigned short* aggb = (unsigned short*)p; p += (size_t)N_NODES * 64 * 2;
    unsigned int* s_pack = (unsigned int*)p; p += (size_t)N_EDGES * 4;
    int* cnt    = (int*)p;  p += (size_t)(N_NODES + 4) * 4;
    int* offs   = (int*)p;  p += (size_t)(N_NODES + 4) * 4;
    int* inc    = (int*)p;  p += (size_t)(N_NODES + 4) * 4;
    int* bsum   = (int*)p;  p += (size_t)256 * 4;
    float* pb_sum = (float*)p; p += (size_t)NB_MLP * 64 * 4;
    float* pb_max = (float*)p; p += (size_t)NB_MLP * 64 * 4;
    float* p2_sum = (float*)p; p += (size_t)NB2 * 64 * 4;
    float* p2_max = (float*)p; p += (size_t)NB2 * 64 * 4;
    unsigned short* w1p = (unsigned short*)p; p += (size_t)3 * 8192 * 2;
    unsigned short* w2p = (unsigned short*)p; p += (size_t)3 * 8192 * 2;
    int* rank = (int*)p;    p += (size_t)N_EDGES * 4;

    hipMemsetAsync(cnt, 0, (N_NODES + 1) * sizeof(int), stream);

    k_node_encode<<<(N_NODES + 3) / 4, 256, 0, stream>>>(x, Wn, bn, zb);
    k_wprep<<<(3 * 8192 + 255) / 256, 256, 0, stream>>>(W1, W2, w1p, w2p);
    k_hist_rank<<<(N_EDGES + 255) / 256, 256, 0, stream>>>(ei, cnt, rank);
    k_scan1<<<SCAN_NB, 256, 0, stream>>>(cnt, inc, bsum);
    k_scan2<<<1, 256, 0, stream>>>(bsum);
    k_scan3<<<SCAN_NB, 256, 0, stream>>>(inc, cnt, bsum, offs);
    k_scatter<<<(N_EDGES + 255) / 256, 256, 0, stream>>>(ei, eattr, offs, rank, s_pack);

    // layer 0
    k_agg<<<(N_NODES + 3) / 4, 256, 0, stream>>>(zb, offs, s_pack, We, be, t, 0, aggb);
    k_mlp<<<NB_MLP, 256, 0, stream>>>(aggb, zb, hb, w1p, w2p, b1, lg, lb, b2,
                                      ng + 64, nb + 64, 0, pb_sum, pb_max);
    // layer 1
    k_agg<<<(N_NODES + 3) / 4, 256, 0, stream>>>(zb, offs, s_pack, We, be, t, 1, aggb);
    k_mlp<<<NB_MLP, 256, 0, stream>>>(aggb, zb, hb, w1p + 8192, w2p + 8192,
                                      b1 + 128, lg + 128, lb + 128, b2 + 64,
                                      ng + 128, nb + 128, 1, pb_sum, pb_max);
    // layer 2
    k_agg<<<(N_NODES + 3) / 4, 256, 0, stream>>>(zb, offs, s_pack, We, be, t, 2, aggb);
    k_mlp<<<NB_MLP, 256, 0, stream>>>(aggb, zb, hb, w1p + 2 * 8192, w2p + 2 * 8192,
                                      b1 + 2 * 128, lg + 2 * 128, lb + 2 * 128, b2 + 2 * 64,
                                      ng, nb, 2, pb_sum, pb_max);

    k_red<<<NB2, 256, 0, stream>>>(pb_sum, pb_max, p2_sum, p2_max);
    k_head<<<1, 256, 0, stream>>>(p2_sum, p2_max, Wl, bl, out);
}

// Round 19
// 348.040 us; speedup vs baseline: 1.0671x; 1.0233x over previous
//
#include <hip/hip_runtime.h>
#include <math.h>

#define N_NODES 50000
#define N_EDGES 1000000
#define HID 64
#define SCAN_NB ((N_NODES + 1 + 255) / 256)
#define N_TILES (N_NODES / 16)          // 3125
#define NB_MLP 512                      // mlp blocks (4 waves each, grid-stride)
#define NB2 64                          // stage-2 reduction blocks
#define VB_S 72                         // vb row stride (ushorts)
#define UB_S 136                        // ub row stride (ushorts)
static_assert(N_NODES % 16 == 0, "tile math");
static_assert(N_NODES <= 65536, "src must fit in 16 bits");

typedef __attribute__((ext_vector_type(8))) short short8;   // 8 bf16 = 4 VGPRs
typedef __attribute__((ext_vector_type(4))) float f32x4;

__device__ __forceinline__ unsigned short f2bf(float x) {   // RNE float->bf16
    unsigned u = __float_as_uint(x);
    u += 0x7FFFu + ((u >> 16) & 1u);
    return (unsigned short)(u >> 16);
}
__device__ __forceinline__ float bfbits_hi(unsigned pk) {
    return __uint_as_float(pk & 0xFFFF0000u);
}
__device__ __forceinline__ float bf2f(unsigned short v) {
    return __uint_as_float(((unsigned)v) << 16);
}
__device__ __forceinline__ unsigned addpk(unsigned a, unsigned b) {
    float lo = __uint_as_float(a << 16) + __uint_as_float(b << 16);
    float hi = __uint_as_float(a & 0xFFFF0000u) + __uint_as_float(b & 0xFFFF0000u);
    return (unsigned)f2bf(lo) | ((unsigned)f2bf(hi) << 16);
}

// ---------------- node encoder: zb = bf16(x @ W_node + b_node) ----------------
__global__ __launch_bounds__(256) void k_node_encode(
    const float* __restrict__ x, const float* __restrict__ Wn,
    const float* __restrict__ bn, unsigned short* __restrict__ zb) {
    int n = blockIdx.x * 4 + (threadIdx.x >> 6);
    int c = threadIdx.x & 63;
    if (n >= N_NODES) return;
    float acc = bn[c];
    const float* xr = x + n * 16;
    #pragma unroll
    for (int k = 0; k < 16; ++k) acc = fmaf(xr[k], Wn[k * 64 + c], acc);
    zb[n * 64 + c] = f2bf(acc);
}

// ---------------- weight prep: pack W1/W2 (3 layers) into bf16 fragment order ----------------
__global__ __launch_bounds__(256) void k_wprep(
    const float* __restrict__ W1, const float* __restrict__ W2,
    unsigned short* __restrict__ w1p, unsigned short* __restrict__ w2p) {
    int i = blockIdx.x * 256 + threadIdx.x;
    if (i >= 3 * 8192) return;
    int L = i >> 13, r = i & 8191;
    int j = r & 7, lane = (r >> 3) & 63;
    int quad = lane >> 4, col = lane & 15;
    {
        int st = r >> 9;                 // s=st>>3 (2), t=st&7 (8)
        int s = st >> 3, t = st & 7;
        w1p[i] = f2bf(W1[L * 8192 + (s * 32 + quad * 8 + j) * 128 + t * 16 + col]);
    }
    {
        int ft = r >> 9;                 // s=ft>>2 (4), t=ft&3 (4)
        int s = ft >> 2, t = ft & 3;
        w2p[i] = f2bf(W2[L * 8192 + (s * 32 + quad * 8 + j) * 64 + t * 16 + col]);
    }
}

// ---------------- edge CSR build: 4-way split histogram (contention /4) ----------------
__global__ __launch_bounds__(256) void k_hist_rank(const int* __restrict__ ei,
                                                   int* __restrict__ cnt4, int* __restrict__ rank) {
    int i = blockIdx.x * blockDim.x + threadIdx.x;
    if (i >= N_EDGES) return;
    int c = i & 3;
    rank[i] = atomicAdd(&cnt4[c * N_NODES + ei[N_EDGES + i]], 1);
}

// totals + inclusive block scan
__global__ __launch_bounds__(256) void k_scan1(const int* __restrict__ cnt4,
                                               int* __restrict__ tot,
                                               int* __restrict__ inc, int* __restrict__ bsum) {
    __shared__ int sh[256];
    int gi = blockIdx.x * 256 + threadIdx.x;
    int v = 0;
    if (gi < N_NODES)
        v = cnt4[gi] + cnt4[N_NODES + gi] + cnt4[2 * N_NODES + gi] + cnt4[3 * N_NODES + gi];
    if (gi < N_NODES + 1) tot[gi] = v;   // gi==N_NODES -> 0
    sh[threadIdx.x] = v;
    __syncthreads();
    #pragma unroll
    for (int d = 1; d < 256; d <<= 1) {
        int t = (threadIdx.x >= d) ? sh[threadIdx.x - d] : 0;
        __syncthreads();
        sh[threadIdx.x] += t;
        __syncthreads();
    }
    if (gi < N_NODES + 1) inc[gi] = sh[threadIdx.x];
    if (threadIdx.x == 255) bsum[blockIdx.x] = sh[255];
}

__global__ __launch_bounds__(256) void k_scan2(int* __restrict__ bsum) {
    __shared__ int sh[256];
    int t = threadIdx.x;
    sh[t] = (t < SCAN_NB) ? bsum[t] : 0;
    __syncthreads();
    #pragma unroll
    for (int d = 1; d < 256; d <<= 1) {
        int v = (t >= d) ? sh[t - d] : 0;
        __syncthreads();
        sh[t] += v;
        __syncthreads();
    }
    if (t < SCAN_NB) bsum[t] = (t == 0) ? 0 : sh[t - 1];
}

// offs (CSR) + per-node sub-counter bases packed as int4
__global__ __launch_bounds__(256) void k_scan3(const int* __restrict__ inc,
                                               const int* __restrict__ tot,
                                               const int* __restrict__ bsum,
                                               const int* __restrict__ cnt4,
                                               int* __restrict__ offs, int4* __restrict__ combined) {
    int gi = blockIdx.x * 256 + threadIdx.x;
    if (gi < N_NODES + 1) {
        int e = bsum[blockIdx.x] + inc[gi] - tot[gi];
        offs[gi] = e;
        if (gi < N_NODES) {
            int c0 = cnt4[gi], c1 = cnt4[N_NODES + gi], c2 = cnt4[2 * N_NODES + gi];
            combined[gi] = make_int4(e, e + c0, e + c0 + c1, e + c0 + c1 + c2);
        }
    }
}

__global__ __launch_bounds__(256) void k_scatter(
    const int* __restrict__ ei, const float* __restrict__ eattr,
    const int4* __restrict__ combined, const int* __restrict__ rank,
    unsigned int* __restrict__ s_pack) {
    int i = blockIdx.x * blockDim.x + threadIdx.x;
    if (i >= N_EDGES) return;
    int d = ei[N_EDGES + i];
    int c = i & 3;
    int4 cb = combined[d];               // one aligned 16B random load
    int base = (c == 0) ? cb.x : (c == 1) ? cb.y : (c == 2) ? cb.z : cb.w;
    int p = base + rank[i];
    unsigned pk = ((unsigned)f2bf(eattr[i]) << 16) | (unsigned)(ei[i] & 0xFFFF);
    s_pack[p] = pk;
}

// ---------------- softmax aggregation (shift-free), one wave/node, 8-edge ILP ----------------
__global__ __launch_bounds__(256) void k_agg(
    const unsigned short* __restrict__ zb, const int* __restrict__ offs,
    const unsigned int* __restrict__ s_pack,
    const float* __restrict__ We, const float* __restrict__ be,
    const float* __restrict__ t, int layer, unsigned short* __restrict__ aggb) {
    int wid = (blockIdx.x * blockDim.x + threadIdx.x) >> 6;
    int lane = threadIdx.x & 63;
    if (wid >= N_NODES) return;
    int beg = offs[wid], end = offs[wid + 1];
    float we = We[lane], bev = be[lane];
    float tl = t[layer];
    float s = 0.f, num = 0.f;
    int i = beg;
    for (; i + 7 < end; i += 8) {
        unsigned pk[8];
        #pragma unroll
        for (int j = 0; j < 8; ++j) pk[j] = s_pack[i + j];
        float zv[8];
        #pragma unroll
        for (int j = 0; j < 8; ++j) zv[j] = bf2f(zb[(pk[j] & 0xFFFFu) * 64 + lane]);
        float acc_s = 0.f, acc_n = 0.f;
        #pragma unroll
        for (int j = 0; j < 8; ++j) {
            float msg = fmaxf(zv[j] + fmaf(bfbits_hi(pk[j]), we, bev), 0.f) + 1e-7f;
            float p = __expf(msg * tl);
            acc_s += p;
            acc_n = fmaf(p, msg, acc_n);
        }
        s += acc_s;
        num += acc_n;
    }
    for (; i < end; ++i) {
        unsigned pk = s_pack[i];
        float zz = bf2f(zb[(pk & 0xFFFFu) * 64 + lane]);
        float msg = fmaxf(zz + fmaf(bfbits_hi(pk), we, bev), 0.f) + 1e-7f;
        float p = __expf(msg * tl);
        s += p;
        num = fmaf(p, msg, num);
    }
    aggb[wid * 64 + lane] = f2bf(num / (s + 1e-16f));
}

// ---------------- MFMA MLP: block-shared weights in LDS, coalesced epilogue ----------------
__global__ __launch_bounds__(256) void k_mlp(
    const unsigned short* __restrict__ aggb, unsigned short* __restrict__ zb,
    unsigned short* __restrict__ hb,
    const unsigned short* __restrict__ w1p, const unsigned short* __restrict__ w2p,
    const float* __restrict__ b1,
    const float* __restrict__ g1, const float* __restrict__ be1,
    const float* __restrict__ b2,
    const float* __restrict__ ng, const float* __restrict__ nb, int mode,
    float* __restrict__ pb_sum, float* __restrict__ pb_max) {
    __shared__ unsigned short w1s[8192];
    __shared__ unsigned short w2s[8192];
    __shared__ unsigned short vbuf[4][16 * VB_S];
    __shared__ unsigned short ubuf[4][16 * UB_S];
    __shared__ float lssum[4][4][16], lsmax[4][4][16];
    int lane = threadIdx.x & 63;
    int wave = threadIdx.x >> 6;
    int col = lane & 15, quad = lane >> 4;
    unsigned short* vb = vbuf[wave];
    unsigned short* ub = ubuf[wave];

    {
        const uint4* s1 = (const uint4*)w1p;
        const uint4* s2 = (const uint4*)w2p;
        uint4* d1 = (uint4*)w1s;
        uint4* d2 = (uint4*)w2s;
        #pragma unroll
        for (int i = 0; i < 4; ++i) {
            d1[threadIdx.x + i * 256] = s1[threadIdx.x + i * 256];
            d2[threadIdx.x + i * 256] = s2[threadIdx.x + i * 256];
        }
    }
    __syncthreads();

    float b1f[8], g1f[8], e1f[8];
    #pragma unroll
    for (int t = 0; t < 8; ++t) {
        int ch = t * 16 + col;
        b1f[t] = b1[ch]; g1f[t] = g1[ch]; e1f[t] = be1[ch];
    }
    float b2f_[4], ngf[4], nbf[4];
    #pragma unroll
    for (int t = 0; t < 4; ++t) {
        b2f_[t] = b2[t * 16 + col];
        ngf[t] = ng[t * 16 + col];
        nbf[t] = nb[t * 16 + col];
    }

    float psum[4] = {0.f, 0.f, 0.f, 0.f};
    float pmax[4] = {0.f, 0.f, 0.f, 0.f};
    int nd = lane >> 2;
    int cg = (lane & 3) * 16;

    for (int tile = blockIdx.x * 4 + wave; tile < N_TILES; tile += NB_MLP * 4) {
        int n0 = tile * 16;
        const uint4* ap = (const uint4*)(aggb + (size_t)(n0 + nd) * 64 + cg);
        const uint4* zp = (const uint4*)(zb + (size_t)(n0 + nd) * 64 + cg);
        uint4 a0 = ap[0], a1 = ap[1], z0 = zp[0], z1 = zp[1];
        uint4 r0, r1;
        r0.x = addpk(a0.x, z0.x); r0.y = addpk(a0.y, z0.y);
        r0.z = addpk(a0.z, z0.z); r0.w = addpk(a0.w, z0.w);
        r1.x = addpk(a1.x, z1.x); r1.y = addpk(a1.y, z1.y);
        r1.z = addpk(a1.z, z1.z); r1.w = addpk(a1.w, z1.w);
        uint4* vdst = (uint4*)&vb[nd * VB_S + cg];
        vdst[0] = r0;
        vdst[1] = r1;

        short8 af0 = *(const short8*)&vb[col * VB_S + quad * 8];
        short8 af1 = *(const short8*)&vb[col * VB_S + 32 + quad * 8];

        uint4 h0, h1;
        if (mode >= 1) {
            const uint4* hp = (const uint4*)(hb + (size_t)(n0 + nd) * 64 + cg);
            h0 = hp[0]; h1 = hp[1];
        }

        f32x4 au[8];
        #pragma unroll
        for (int t = 0; t < 8; ++t) {
            short8 w0 = *(const short8*)&w1s[((0 * 8 + t) * 64 + lane) * 8];
            short8 w1 = *(const short8*)&w1s[((1 * 8 + t) * 64 + lane) * 8];
            f32x4 c = {0.f, 0.f, 0.f, 0.f};
            c = __builtin_amdgcn_mfma_f32_16x16x32_bf16(af0, w0, c, 0, 0, 0);
            c = __builtin_amdgcn_mfma_f32_16x16x32_bf16(af1, w1, c, 0, 0, 0);
            au[t] = c;
        }
        #pragma unroll
        for (int r = 0; r < 4; ++r) {
            float sx = 0.f, sq = 0.f;
            #pragma unroll
            for (int t = 0; t < 8; ++t) {
                float v = au[t][r] + b1f[t];
                sx += v; sq += v * v;
            }
            #pragma unroll
            for (int mask = 1; mask < 16; mask <<= 1) {
                sx += __shfl_xor(sx, mask, 64);
                sq += __shfl_xor(sq, mask, 64);
            }
            float mu = sx * (1.f / 128.f);
            float var = sq * (1.f / 128.f) - mu * mu;
            float rs = rsqrtf(var + 1e-5f);
            int row = quad * 4 + r;
            #pragma unroll
            for (int t = 0; t < 8; ++t) {
                float v = au[t][r] + b1f[t];
                float y = fmaxf(fmaf((v - mu) * rs, g1f[t], e1f[t]), 0.f);
                ub[row * UB_S + t * 16 + col] = f2bf(y);
            }
        }
        f32x4 oc[4];
        #pragma unroll
        for (int t = 0; t < 4; ++t) oc[t] = (f32x4){0.f, 0.f, 0.f, 0.f};
        #pragma unroll
        for (int s = 0; s < 4; ++s) {
            short8 a = *(const short8*)&ub[col * UB_S + s * 32 + quad * 8];
            #pragma unroll
            for (int t = 0; t < 4; ++t) {
                short8 w = *(const short8*)&w2s[((s * 4 + t) * 64 + lane) * 8];
                oc[t] = __builtin_amdgcn_mfma_f32_16x16x32_bf16(a, w, oc[t], 0, 0, 0);
            }
        }
        if (mode >= 1) {
            uint4* hdst = (uint4*)&vb[nd * VB_S + cg];
            hdst[0] = h0;
            hdst[1] = h1;
        }
        #pragma unroll
        for (int r = 0; r < 4; ++r) {
            int row = quad * 4 + r;
            float val[4];
            #pragma unroll
            for (int t = 0; t < 4; ++t) {
                val[t] = oc[t][r] + b2f_[t];
                if (mode >= 1) val[t] += bf2f(vb[row * VB_S + t * 16 + col]);
            }
            float sx = 0.f, sq = 0.f;
            #pragma unroll
            for (int t = 0; t < 4; ++t) { sx += val[t]; sq += val[t] * val[t]; }
            #pragma unroll
            for (int mask = 1; mask < 16; mask <<= 1) {
                sx += __shfl_xor(sx, mask, 64);
                sq += __shfl_xor(sq, mask, 64);
            }
            float mu = sx * (1.f / 64.f);
            float var = sq * (1.f / 64.f) - mu * mu;
            float rs = rsqrtf(var + 1e-5f);
            #pragma unroll
            for (int t = 0; t < 4; ++t) {
                float y = fmaxf(fmaf((val[t] - mu) * rs, ngf[t], nbf[t]), 0.f);
                if (mode <= 1) {
                    vb[row * VB_S + t * 16 + col] = f2bf(val[t]);   // h
                    ub[row * UB_S + t * 16 + col] = f2bf(y);        // z
                } else {
                    psum[t] += y;
                    pmax[t] = fmaxf(pmax[t], y);
                }
            }
        }
        if (mode <= 1) {
            const uint4* hsrc = (const uint4*)&vb[nd * VB_S + cg];
            const uint4* zsrc = (const uint4*)&ub[nd * UB_S + cg];
            uint4* hdst = (uint4*)(hb + (size_t)(n0 + nd) * 64 + cg);
            uint4* zdst = (uint4*)(zb + (size_t)(n0 + nd) * 64 + cg);
            hdst[0] = hsrc[0]; hdst[1] = hsrc[1];
            zdst[0] = zsrc[0]; zdst[1] = zsrc[1];
        }
    }
    if (mode == 2) {
        #pragma unroll
        for (int t = 0; t < 4; ++t) {
            psum[t] += __shfl_xor(psum[t], 16, 64);
            psum[t] += __shfl_xor(psum[t], 32, 64);
            pmax[t] = fmaxf(pmax[t], __shfl_xor(pmax[t], 16, 64));
            pmax[t] = fmaxf(pmax[t], __shfl_xor(pmax[t], 32, 64));
        }
        if (quad == 0) {
            #pragma unroll
            for (int t = 0; t < 4; ++t) {
                lssum[wave][t][col] = psum[t];
                lsmax[wave][t][col] = pmax[t];
            }
        }
        __syncthreads();
        if (wave == 0) {
            int t = lane >> 4, c = lane & 15;
            float s = lssum[0][t][c] + lssum[1][t][c] + lssum[2][t][c] + lssum[3][t][c];
            float mx = fmaxf(fmaxf(lsmax[0][t][c], lsmax[1][t][c]),
                             fmaxf(lsmax[2][t][c], lsmax[3][t][c]));
            pb_sum[blockIdx.x * 64 + lane] = s;
            pb_max[blockIdx.x * 64 + lane] = mx;
        }
    }
}

// ---------------- stage-2 reduce: NB_MLP partial rows -> 64 rows ----------------
__global__ __launch_bounds__(256) void k_red(
    const float* __restrict__ pb_sum, const float* __restrict__ pb_max,
    float* __restrict__ p2_sum, float* __restrict__ p2_max) {
    __shared__ float sa4[4][64], sm4[4][64];
    int t = threadIdx.x;
    int ch = t & 63, part = t >> 6;
    float s = 0.f, mx = 0.f;
    for (int b = blockIdx.x + NB2 * part; b < NB_MLP; b += NB2 * 4) {
        s += pb_sum[b * 64 + ch];
        mx = fmaxf(mx, pb_max[b * 64 + ch]);
    }
    sa4[part][ch] = s; sm4[part][ch] = mx;
    __syncthreads();
    if (t < 64) {
        p2_sum[blockIdx.x * 64 + t] = sa4[0][t] + sa4[1][t] + sa4[2][t] + sa4[3][t];
        p2_max[blockIdx.x * 64 + t] =
            fmaxf(fmaxf(sm4[0][t], sm4[1][t]), fmaxf(sm4[2][t], sm4[3][t]));
    }
}

// ---------------- head ----------------
__global__ __launch_bounds__(256) void k_head(
    const float* __restrict__ p2_sum, const float* __restrict__ p2_max,
    const float* __restrict__ Wl, const float* __restrict__ bl, float* __restrict__ out) {
    __shared__ float sa4[4][64], sm4[4][64];
    __shared__ float sa[64], sm[64], emb[64];
    int t = threadIdx.x;
    int ch = t & 63, part = t >> 6;
    float s = 0.f, mx = 0.f;
    for (int b = part; b < NB2; b += 4) {
        s += p2_sum[b * 64 + ch];
        mx = fmaxf(mx, p2_max[b * 64 + ch]);
    }
    sa4[part][ch] = s; sm4[part][ch] = mx;
    __syncthreads();
    if (t < 64) {
        sa[t] = sa4[0][t] + sa4[1][t] + sa4[2][t] + sa4[3][t];
        sm[t] = fmaxf(fmaxf(sm4[0][t], sm4[1][t]), fmaxf(sm4[2][t], sm4[3][t]));
    }
    __syncthreads();
    if (t < 64) {
        if (t < 32) {
            emb[t] = (sa[2 * t] + sa[2 * t + 1]) * (0.5f / (float)N_NODES);
        } else {
            int i = t - 32;
            emb[t] = fmaxf(sm[2 * i], sm[2 * i + 1]);
        }
    }
    __syncthreads();
    if (t < 64) {
        float acc = bl[t];
        for (int k = 0; k < 64; ++k) acc = fmaf(emb[k], Wl[k * 64 + t], acc);
        out[t] = acc;
    }
}

extern "C" void kernel_launch(void* const* d_in, const int* in_sizes, int n_in,
                              void* d_out, int out_size, void* d_ws, size_t ws_size,
                              hipStream_t stream) {
    const float* x     = (const float*)d_in[0];
    const float* eattr = (const float*)d_in[1];
    const int*   ei    = (const int*)d_in[2];
    const float* Wn    = (const float*)d_in[3];
    const float* bn    = (const float*)d_in[4];
    const float* We    = (const float*)d_in[5];
    const float* be    = (const float*)d_in[6];
    const float* t     = (const float*)d_in[7];
    const float* W1    = (const float*)d_in[8];
    const float* b1    = (const float*)d_in[9];
    const float* lg    = (const float*)d_in[10];
    const float* lb    = (const float*)d_in[11];
    const float* W2    = (const float*)d_in[12];
    const float* b2    = (const float*)d_in[13];
    const float* ng    = (const float*)d_in[14];
    const float* nb    = (const float*)d_in[15];
    const float* Wl    = (const float*)d_in[16];
    const float* bl    = (const float*)d_in[17];
    float* out = (float*)d_out;

    char* p = (char*)d_ws;
    unsigned short* hb   = (unsigned short*)p; p += (size_t)N_NODES * 64 * 2;
    unsigned short* zb   = (unsigned short*)p; p += (size_t)N_NODES * 64 * 2;
    unsigned short* aggb = (unsigned short*)p; p += (size_t)N_NODES * 64 * 2;
    unsigned int* s_pack = (unsigned int*)p; p += (size_t)N_EDGES * 4;
    int* cnt4   = (int*)p;  p += (size_t)4 * N_NODES * 4;
    int* tot    = (int*)p;  p += (size_t)(N_NODES + 4) * 4;
    int* offs   = (int*)p;  p += (size_t)(N_NODES + 4) * 4;
    int* inc    = (int*)p;  p += (size_t)(N_NODES + 4) * 4;
    int* bsum   = (int*)p;  p += (size_t)256 * 4;
    int4* combined = (int4*)p; p += (size_t)N_NODES * 16;
    float* pb_sum = (float*)p; p += (size_t)NB_MLP * 64 * 4;
    float* pb_max = (float*)p; p += (size_t)NB_MLP * 64 * 4;
    float* p2_sum = (float*)p; p += (size_t)NB2 * 64 * 4;
    float* p2_max = (float*)p; p += (size_t)NB2 * 64 * 4;
    unsigned short* w1p = (unsigned short*)p; p += (size_t)3 * 8192 * 2;
    unsigned short* w2p = (unsigned short*)p; p += (size_t)3 * 8192 * 2;
    int* rank = (int*)p;    p += (size_t)N_EDGES * 4;

    hipMemsetAsync(cnt4, 0, (size_t)4 * N_NODES * sizeof(int), stream);

    k_node_encode<<<(N_NODES + 3) / 4, 256, 0, stream>>>(x, Wn, bn, zb);
    k_wprep<<<(3 * 8192 + 255) / 256, 256, 0, stream>>>(W1, W2, w1p, w2p);
    k_hist_rank<<<(N_EDGES + 255) / 256, 256, 0, stream>>>(ei, cnt4, rank);
    k_scan1<<<SCAN_NB, 256, 0, stream>>>(cnt4, tot, inc, bsum);
    k_scan2<<<1, 256, 0, stream>>>(bsum);
    k_scan3<<<SCAN_NB, 256, 0, stream>>>(inc, tot, bsum, cnt4, offs, combined);
    k_scatter<<<(N_EDGES + 255) / 256, 256, 0, stream>>>(ei, eattr, combined, rank, s_pack);

    // layer 0
    k_agg<<<(N_NODES + 3) / 4, 256, 0, stream>>>(zb, offs, s_pack, We, be, t, 0, aggb);
    k_mlp<<<NB_MLP, 256, 0, stream>>>(aggb, zb, hb, w1p, w2p, b1, lg, lb, b2,
                                      ng + 64, nb + 64, 0, pb_sum, pb_max);
    // layer 1
    k_agg<<<(N_NODES + 3) / 4, 256, 0, stream>>>(zb, offs, s_pack, We, be, t, 1, aggb);
    k_mlp<<<NB_MLP, 256, 0, stream>>>(aggb, zb, hb, w1p + 8192, w2p + 8192,
                                      b1 + 128, lg + 128, lb + 128, b2 + 64,
                                      ng + 128, nb + 128, 1, pb_sum, pb_max);
    // layer 2
    k_agg<<<(N_NODES + 3) / 4, 256, 0, stream>>>(zb, offs, s_pack, We, be, t, 2, aggb);
    k_mlp<<<NB_MLP, 256, 0, stream>>>(aggb, zb, hb, w1p + 2 * 8192, w2p + 2 * 8192,
                                      b1 + 2 * 128, lg + 2 * 128, lb + 2 * 128, b2 + 2 * 64,
                                      ng, nb, 2, pb_sum, pb_max);

    k_red<<<NB2, 256, 0, stream>>>(pb_sum, pb_max, p2_sum, p2_max);
    k_head<<<1, 256, 0, stream>>>(p2_sum, p2_max, Wl, bl, out);
}